// Round 2
// baseline (22323.895 us; speedup 1.0000x reference)
//
#include <hip/hip_runtime.h>
#include <math.h>

#define B_   2
#define S_   2048
#define D_   2048
#define H_   16
#define KVH_ 4
#define HD_  128
#define REP_ 4

typedef __attribute__((ext_vector_type(8))) short bf16x8;
typedef __attribute__((ext_vector_type(4))) float f32x4;

__device__ inline unsigned short f2bf(float x) {
    union { float f; unsigned u; } v; v.f = x;
    unsigned r = v.u + 0x7FFF + ((v.u >> 16) & 1);   // RNE
    return (unsigned short)(r >> 16);
}

// ---------------------------------------------------------------------------
// Kernel 1: fused QKV projection (fp32 compute) + fused RoPE + bf16 cast.
// Q -> Qh (B,H,S,HD) bf16, K -> Kh (B,KVH,S,HD) bf16 (both RoPE'd),
// V -> Vt (B,KVH,HD,S) bf16 TRANSPOSED (scattered 2B writes, small matrix).
// ---------------------------------------------------------------------------
__global__ __launch_bounds__(256) void qkv_gemm(
    const float* __restrict__ x,
    const float* __restrict__ Wq, const float* __restrict__ Wk,
    const float* __restrict__ Wv,
    unsigned short* __restrict__ Qh, unsigned short* __restrict__ Kh,
    unsigned short* __restrict__ Vt)
{
    const int bm  = blockIdx.x;           // 0..31  (M/128)
    const int bn  = blockIdx.y;           // 0..23  (3072/128)
    const int tid = threadIdx.x;
    const int tx  = tid & 15, ty = tid >> 4;

    const int row0 = bm * 128;
    const int n0   = bn * 128;

    const float* Wp; int ldw; int wc0;
    if (n0 < 2048)      { Wp = Wq; ldw = 2048; wc0 = n0; }
    else if (n0 < 2560) { Wp = Wk; ldw = 512;  wc0 = n0 - 2048; }
    else                { Wp = Wv; ldw = 512;  wc0 = n0 - 2560; }

    __shared__ float As[8][128];
    __shared__ float Bs[8][128];

    float acc[8][8];
    #pragma unroll
    for (int i = 0; i < 8; ++i)
        #pragma unroll
        for (int j = 0; j < 8; ++j) acc[i][j] = 0.0f;

    const int am = tid >> 1;
    const int ak = (tid & 1) * 4;
    const int bk = tid >> 5;
    const int bq = (tid & 31) * 4;

    for (int kt = 0; kt < 2048; kt += 8) {
        float4 av = *(const float4*)&x [(size_t)(row0 + am) * 2048 + kt + ak];
        float4 bv = *(const float4*)&Wp[(size_t)(kt + bk) * ldw + wc0 + bq];
        __syncthreads();
        As[ak + 0][am] = av.x; As[ak + 1][am] = av.y;
        As[ak + 2][am] = av.z; As[ak + 3][am] = av.w;
        *(float4*)&Bs[bk][bq] = bv;
        __syncthreads();
        #pragma unroll
        for (int kk = 0; kk < 8; ++kk) {
            float4 a0 = *(const float4*)&As[kk][ty * 8];
            float4 a1 = *(const float4*)&As[kk][ty * 8 + 4];
            float4 b0 = *(const float4*)&Bs[kk][tx * 8];
            float4 b1 = *(const float4*)&Bs[kk][tx * 8 + 4];
            float a[8] = {a0.x,a0.y,a0.z,a0.w,a1.x,a1.y,a1.z,a1.w};
            float b[8] = {b0.x,b0.y,b0.z,b0.w,b1.x,b1.y,b1.z,b1.w};
            #pragma unroll
            for (int i = 0; i < 8; ++i)
                #pragma unroll
                for (int j = 0; j < 8; ++j)
                    acc[i][j] += a[i] * b[j];
        }
    }

    // ---- epilogue: RoPE (Q/K) + bf16 cast; V -> transposed scatter ----
    if (n0 < 2560) {
        // Q or K head: 128 cols of this block == one head; d = tx*8+j.
        // RoPE pair (d, d+64) lives in lane^8 (same wave).
        const bool isQ = (n0 < 2048);
        const int h = isQ ? (n0 >> 7) : ((n0 - 2048) >> 7);
        #pragma unroll
        for (int i = 0; i < 8; ++i) {
            int m  = row0 + ty * 8 + i;
            int bb = m >> 11;
            int s  = m & 2047;
            unsigned short outv[8];
            #pragma unroll
            for (int j = 0; j < 8; ++j) {
                int d = tx * 8 + j;
                float partner = __shfl_xor(acc[i][j], 8);
                int dm = d & 63;
                // inv = 10000^(-dm/64) via exp2 with high-precision constant
                float inv = exp2f(-(float)dm * 0.20761871093344086f); // log2(1e4)/64
                float ang = (float)s * inv;
                float sn, c;
                sincosf(ang, &sn, &c);
                float val = (d < 64) ? (acc[i][j] * c - partner * sn)
                                     : (acc[i][j] * c + partner * sn);
                outv[j] = f2bf(val);
            }
            unsigned short* dst = isQ
                ? Qh + (((size_t)bb * H_   + h) * S_ + s) * HD_ + tx * 8
                : Kh + (((size_t)bb * KVH_ + h) * S_ + s) * HD_ + tx * 8;
            *(bf16x8*)dst = *(bf16x8*)outv;
        }
    } else {
        const int g = (n0 - 2560) >> 7;
        #pragma unroll
        for (int i = 0; i < 8; ++i) {
            int m  = row0 + ty * 8 + i;
            int bb = m >> 11;
            int s  = m & 2047;
            unsigned short* base = Vt + (((size_t)bb * KVH_ + g) * HD_) * S_;
            #pragma unroll
            for (int j = 0; j < 8; ++j) {
                int d = tx * 8 + j;
                base[(size_t)d * S_ + s] = f2bf(acc[i][j]);
            }
        }
    }
}

// ---------------------------------------------------------------------------
// Kernel 2: bf16 MFMA flash attention (causal, GQA).
// Block = 256 threads = 4 waves; block owns a 64-row Q tile of one (b,h);
// wave w owns q-rows [q0+16w, q0+16w+16). mfma_f32_16x16x32_bf16 throughout.
// A-frag: A[m=lane&15][k=quad*8+j]; B-frag: B[k=quad*8+j][n=lane&15];
// C/D: row=quad*4+reg, col=lane&15 (m89-verified).
// ---------------------------------------------------------------------------
__global__ __launch_bounds__(256) void flash_attn_mfma(
    const unsigned short* __restrict__ Qh,
    const unsigned short* __restrict__ Kh,
    const unsigned short* __restrict__ Vt,
    float* __restrict__ att)
{
    const int qt   = 31 - blockIdx.x;      // heavy tiles first
    const int bh   = blockIdx.y;
    const int b    = bh >> 4, h = bh & 15;
    const int g    = h >> 2;
    const int tid  = threadIdx.x;
    const int w    = tid >> 6;             // wave 0..3
    const int lane = tid & 63;
    const int lo16 = lane & 15;
    const int quad = lane >> 4;

    const int q0 = qt * 64;

    const unsigned short* Qb = Qh + (((size_t)b * H_   + h) * S_) * HD_;
    const unsigned short* Kb = Kh + (((size_t)b * KVH_ + g) * S_) * HD_;
    const unsigned short* Vb = Vt + (((size_t)b * KVH_ + g) * HD_) * S_;

    // padded strides: 136 (=17*8) and 72 (=9*8) keep b128 rows 16B-aligned
    // and bank aliasing <=2-way (free).
    __shared__ __align__(16) unsigned short Ks[64][136];
    __shared__ __align__(16) unsigned short Vs[128][72];
    __shared__ __align__(16) unsigned short Ps[4][16][72];

    // Q fragments: loop-invariant, straight from global to registers
    bf16x8 qf[4];
    #pragma unroll
    for (int kc = 0; kc < 4; ++kc)
        qf[kc] = *(const bf16x8*)(Qb + (size_t)(q0 + w * 16 + lo16) * HD_
                                     + kc * 32 + quad * 8);

    f32x4 o[8];
    #pragma unroll
    for (int n = 0; n < 8; ++n) o[n] = (f32x4){0.f, 0.f, 0.f, 0.f};
    float m_run[4], l_run[4];
    #pragma unroll
    for (int r = 0; r < 4; ++r) { m_run[r] = -1e30f; l_run[r] = 0.0f; }

    const float scale = 0.08838834764831845f;  // 1/sqrt(128)

    for (int kt = 0; kt <= qt; ++kt) {
        const int k0 = kt * 64;
        __syncthreads();                       // prior PV reads complete
        // stage K tile: 64 rows x 256B, full rows per wave-instr
        #pragma unroll
        for (int it = 0; it < 4; ++it) {
            int u = it * 256 + tid;
            int r = u >> 4, ch = u & 15;
            bf16x8 v = *(const bf16x8*)(Kb + (size_t)(k0 + r) * HD_ + ch * 8);
            *(bf16x8*)&Ks[r][ch * 8] = v;
        }
        // stage V tile (already transposed in global): 128 rows x 128B
        #pragma unroll
        for (int it = 0; it < 4; ++it) {
            int u = it * 256 + tid;
            int d = u >> 3, ch = u & 7;
            bf16x8 v = *(const bf16x8*)(Vb + (size_t)d * S_ + k0 + ch * 8);
            *(bf16x8*)&Vs[d][ch * 8] = v;
        }
        __syncthreads();

        // S strip (16x64) = Q_strip (16x128) . K^T
        f32x4 sc[4];
        #pragma unroll
        for (int cb = 0; cb < 4; ++cb) sc[cb] = (f32x4){0.f, 0.f, 0.f, 0.f};
        #pragma unroll
        for (int kc = 0; kc < 4; ++kc) {
            #pragma unroll
            for (int cb = 0; cb < 4; ++cb) {
                bf16x8 kf = *(const bf16x8*)&Ks[cb * 16 + lo16][kc * 32 + quad * 8];
                sc[cb] = __builtin_amdgcn_mfma_f32_16x16x32_bf16(qf[kc], kf, sc[cb], 0, 0, 0);
            }
        }

        // mask + online softmax (row r of strip lives in quad*4+r across 16 lanes)
        const bool diag = (kt == qt);
        #pragma unroll
        for (int r = 0; r < 4; ++r) {
            int qrow = q0 + w * 16 + quad * 4 + r;
            float sv[4];
            #pragma unroll
            for (int cb = 0; cb < 4; ++cb) {
                float xv = sc[cb][r] * scale;
                if (diag && (k0 + cb * 16 + lo16) > qrow) xv = -1e30f;
                sv[cb] = xv;
            }
            float mt = fmaxf(fmaxf(sv[0], sv[1]), fmaxf(sv[2], sv[3]));
            #pragma unroll
            for (int off = 1; off < 16; off <<= 1)
                mt = fmaxf(mt, __shfl_xor(mt, off));
            float m_new = fmaxf(m_run[r], mt);
            float alpha = __expf(m_run[r] - m_new);
            float psum = 0.0f;
            #pragma unroll
            for (int cb = 0; cb < 4; ++cb) {
                float p = __expf(sv[cb] - m_new);
                psum += p;
                Ps[w][quad * 4 + r][cb * 16 + lo16] = f2bf(p);
            }
            #pragma unroll
            for (int off = 1; off < 16; off <<= 1)
                psum += __shfl_xor(psum, off);
            m_run[r] = m_new;
            l_run[r] = l_run[r] * alpha + psum;
            #pragma unroll
            for (int n = 0; n < 8; ++n) o[n][r] *= alpha;
        }
        // no barrier: Ps[w] is wave-private; lgkmcnt ordering handles RAW

        // O strip (16x128) += P (16x64) . V (64x128)
        #pragma unroll
        for (int kc = 0; kc < 2; ++kc) {
            bf16x8 pf = *(const bf16x8*)&Ps[w][lo16][kc * 32 + quad * 8];
            #pragma unroll
            for (int n = 0; n < 8; ++n) {
                bf16x8 vf = *(const bf16x8*)&Vs[n * 16 + lo16][kc * 32 + quad * 8];
                o[n] = __builtin_amdgcn_mfma_f32_16x16x32_bf16(pf, vf, o[n], 0, 0, 0);
            }
        }
    }

    // epilogue: att (B, S, H*HD) fp32
    #pragma unroll
    for (int r = 0; r < 4; ++r) {
        int srow   = q0 + w * 16 + quad * 4 + r;
        float invl = 1.0f / l_run[r];
        float* dst = att + ((size_t)b * S_ + srow) * D_ + h * HD_;
        #pragma unroll
        for (int n = 0; n < 8; ++n)
            dst[n * 16 + lo16] = o[n][r] * invl;
    }
}

// ---------------------------------------------------------------------------
// Kernel 3: output projection (fp32). out = att[4096][2048] @ Wo[2048][2048]
// ---------------------------------------------------------------------------
__global__ __launch_bounds__(256) void out_gemm(
    const float* __restrict__ A, const float* __restrict__ Wo,
    float* __restrict__ C)
{
    const int bm  = blockIdx.x;
    const int bn  = blockIdx.y;
    const int tid = threadIdx.x;
    const int tx  = tid & 15, ty = tid >> 4;
    const int row0 = bm * 128;
    const int n0   = bn * 128;

    __shared__ float As[8][128];
    __shared__ float Bs[8][128];

    float acc[8][8];
    #pragma unroll
    for (int i = 0; i < 8; ++i)
        #pragma unroll
        for (int j = 0; j < 8; ++j) acc[i][j] = 0.0f;

    const int am = tid >> 1;
    const int ak = (tid & 1) * 4;
    const int bk = tid >> 5;
    const int bq = (tid & 31) * 4;

    for (int kt = 0; kt < 2048; kt += 8) {
        float4 av = *(const float4*)&A [(size_t)(row0 + am) * 2048 + kt + ak];
        float4 bv = *(const float4*)&Wo[(size_t)(kt + bk) * 2048 + n0 + bq];
        __syncthreads();
        As[ak + 0][am] = av.x; As[ak + 1][am] = av.y;
        As[ak + 2][am] = av.z; As[ak + 3][am] = av.w;
        *(float4*)&Bs[bk][bq] = bv;
        __syncthreads();
        #pragma unroll
        for (int kk = 0; kk < 8; ++kk) {
            float4 a0 = *(const float4*)&As[kk][ty * 8];
            float4 a1 = *(const float4*)&As[kk][ty * 8 + 4];
            float4 b0 = *(const float4*)&Bs[kk][tx * 8];
            float4 b1 = *(const float4*)&Bs[kk][tx * 8 + 4];
            float a[8] = {a0.x,a0.y,a0.z,a0.w,a1.x,a1.y,a1.z,a1.w};
            float b[8] = {b0.x,b0.y,b0.z,b0.w,b1.x,b1.y,b1.z,b1.w};
            #pragma unroll
            for (int i = 0; i < 8; ++i)
                #pragma unroll
                for (int j = 0; j < 8; ++j)
                    acc[i][j] += a[i] * b[j];
        }
    }

    #pragma unroll
    for (int i = 0; i < 8; ++i) {
        size_t m = (size_t)(row0 + ty * 8 + i);
        float* dst = C + m * 2048 + n0 + tx * 8;
        *(float4*)dst       = make_float4(acc[i][0], acc[i][1], acc[i][2], acc[i][3]);
        *(float4*)(dst + 4) = make_float4(acc[i][4], acc[i][5], acc[i][6], acc[i][7]);
    }
}

// ---------------------------------------------------------------------------
extern "C" void kernel_launch(void* const* d_in, const int* in_sizes, int n_in,
                              void* d_out, int out_size, void* d_ws, size_t ws_size,
                              hipStream_t stream)
{
    const float* x  = (const float*)d_in[0];
    const float* Wq = (const float*)d_in[1];
    const float* Wk = (const float*)d_in[2];
    const float* Wv = (const float*)d_in[3];
    const float* Wo = (const float*)d_in[4];
    float* out = (float*)d_out;

    // ws layout: Qh bf16 8.4M | Kh bf16 2.1M | Vt bf16 2.1M | att fp32 8.4M  (~59 MB)
    unsigned short* Qh = (unsigned short*)d_ws;
    unsigned short* Kh = Qh + (size_t)B_ * H_   * S_ * HD_;
    unsigned short* Vt = Kh + (size_t)B_ * KVH_ * S_ * HD_;
    float*          att = (float*)(Vt + (size_t)B_ * KVH_ * S_ * HD_);

    dim3 g1(32, 24);
    qkv_gemm<<<g1, 256, 0, stream>>>(x, Wq, Wk, Wv, Qh, Kh, Vt);

    dim3 g2(32, 32);   // (q-tiles reversed, B*H)
    flash_attn_mfma<<<g2, 256, 0, stream>>>(Qh, Kh, Vt, att);

    dim3 g3(32, 16);
    out_gemm<<<g3, 256, 0, stream>>>(att, Wo, out);
}

// Round 3
// 551.222 us; speedup vs baseline: 40.4989x; 40.4989x over previous
//
#include <hip/hip_runtime.h>
#include <math.h>

#define B_   2
#define S_   2048
#define D_   2048
#define H_   16
#define KVH_ 4
#define HD_  128
#define REP_ 4

typedef __attribute__((ext_vector_type(8))) short bf16x8;
typedef __attribute__((ext_vector_type(4))) short bf16x4;
typedef __attribute__((ext_vector_type(4))) float f32x4;

__device__ __forceinline__ unsigned short f2bf(float x) {
    union { float f; unsigned u; } v; v.f = x;
    unsigned r = v.u + 0x7FFF + ((v.u >> 16) & 1);   // RNE
    return (unsigned short)(r >> 16);
}

// async global->LDS, 16B per lane; LDS dest is wave-uniform base + lane*16
__device__ __forceinline__ void gl_lds16(const unsigned short* g, unsigned short* l) {
    __builtin_amdgcn_global_load_lds(
        (const __attribute__((address_space(1))) unsigned int*)g,
        (__attribute__((address_space(3))) unsigned int*)l,
        16, 0, 0);
}

// ---------------------------------------------------------------------------
// cast fp32 -> bf16 (elementwise, n % 4 == 0)
// ---------------------------------------------------------------------------
__global__ void cast_bf16(const float* __restrict__ src,
                          unsigned short* __restrict__ dst, int n4)
{
    int i = blockIdx.x * 256 + threadIdx.x;
    if (i >= n4) return;
    float4 v = *(const float4*)&src[(size_t)i * 4];
    bf16x4 o;
    o[0] = (short)f2bf(v.x); o[1] = (short)f2bf(v.y);
    o[2] = (short)f2bf(v.z); o[3] = (short)f2bf(v.w);
    *(bf16x4*)&dst[(size_t)i * 4] = o;
}

// ---------------------------------------------------------------------------
// cast + transpose: src [R][C] fp32 -> dst [C][R] bf16.  32x32 LDS tiles.
// ---------------------------------------------------------------------------
__global__ __launch_bounds__(256) void cast_transpose(
    const float* __restrict__ src, unsigned short* __restrict__ dst,
    int R, int C)
{
    __shared__ float T[32][33];
    const int bi = blockIdx.x;   // along R
    const int bj = blockIdx.y;   // along C
    const int t  = threadIdx.x;
    const int r  = t >> 3, cq = (t & 7) * 4;

    float4 v = *(const float4*)&src[(size_t)(bi * 32 + r) * C + bj * 32 + cq];
    T[r][cq + 0] = v.x; T[r][cq + 1] = v.y;
    T[r][cq + 2] = v.z; T[r][cq + 3] = v.w;
    __syncthreads();

    bf16x4 o;
    o[0] = (short)f2bf(T[cq + 0][r]);
    o[1] = (short)f2bf(T[cq + 1][r]);
    o[2] = (short)f2bf(T[cq + 2][r]);
    o[3] = (short)f2bf(T[cq + 3][r]);
    *(bf16x4*)&dst[(size_t)(bj * 32 + r) * R + bi * 32 + cq] = o;
}

// ---------------------------------------------------------------------------
// Kernel: fused QKV projection, bf16 MFMA (m97 structure).
// C[4096][3072] = xh[4096][2048] . Wt[n][k]^T, RoPE fused, outputs:
//   Qh (B,H,S,HD) bf16, Kh (B,KVH,S,HD) bf16, Vt (B,KVH,HD,S) bf16.
// 256 thr = 4 waves; wave w owns rows w*32..w*32+31 (2 strips), all 128 cols.
// V blocks transpose through LDS (Ts, unioned with As/Bs) -> coalesced b128.
// ---------------------------------------------------------------------------
__global__ __launch_bounds__(256) void qkv_mfma(
    const unsigned short* __restrict__ Ah,    // xh [4096][2048]
    const unsigned short* __restrict__ Wqt,   // [2048][2048]
    const unsigned short* __restrict__ Wkt,   // [512][2048]
    const unsigned short* __restrict__ Wvt,   // [512][2048]
    unsigned short* __restrict__ Qh, unsigned short* __restrict__ Kh,
    unsigned short* __restrict__ Vt)
{
    __shared__ __align__(16) char smem[34816];
    unsigned short* As = (unsigned short*)smem;            // [128][32] unpadded
    unsigned short* Bs = (unsigned short*)(smem + 8192);   // [128][32] unpadded
    unsigned short* Ts = (unsigned short*)smem;            // [128][136] (V only)

    const int bm = blockIdx.x, bn = blockIdx.y;
    const int m0 = bm * 128, n0 = bn * 128;
    const int tid  = threadIdx.x;
    const int w    = tid >> 6;
    const int lane = tid & 63;
    const int lo16 = lane & 15, quad = lane >> 4;

    const unsigned short* Bt;
    if (n0 < 2048)      Bt = Wqt + (size_t)n0 * 2048;
    else if (n0 < 2560) Bt = Wkt + (size_t)(n0 - 2048) * 2048;
    else                Bt = Wvt + (size_t)(n0 - 2560) * 2048;

    const unsigned short* Ag = Ah + (size_t)m0 * 2048;

    f32x4 acc[2][8];
    #pragma unroll
    for (int i = 0; i < 2; ++i)
        #pragma unroll
        for (int j = 0; j < 8; ++j) acc[i][j] = (f32x4){0.f, 0.f, 0.f, 0.f};

    const int srow = w * 32 + (lane >> 2);   // staging row (16 rows/call)
    const int scol = (lane & 3) * 8;         // staging k-chunk (8 el = 16B)

    for (int kt = 0; kt < 2048; kt += 32) {
        __syncthreads();
        gl_lds16(Ag + (size_t)(srow     ) * 2048 + kt + scol, As + (w * 32     ) * 32);
        gl_lds16(Ag + (size_t)(srow + 16) * 2048 + kt + scol, As + (w * 32 + 16) * 32);
        gl_lds16(Bt + (size_t)(srow     ) * 2048 + kt + scol, Bs + (w * 32     ) * 32);
        gl_lds16(Bt + (size_t)(srow + 16) * 2048 + kt + scol, Bs + (w * 32 + 16) * 32);
        __syncthreads();

        bf16x8 a0 = *(const bf16x8*)&As[(w * 32      + lo16) * 32 + quad * 8];
        bf16x8 a1 = *(const bf16x8*)&As[(w * 32 + 16 + lo16) * 32 + quad * 8];
        #pragma unroll
        for (int jj = 0; jj < 8; ++jj) {
            bf16x8 b = *(const bf16x8*)&Bs[(jj * 16 + lo16) * 32 + quad * 8];
            acc[0][jj] = __builtin_amdgcn_mfma_f32_16x16x32_bf16(a0, b, acc[0][jj], 0, 0, 0);
            acc[1][jj] = __builtin_amdgcn_mfma_f32_16x16x32_bf16(a1, b, acc[1][jj], 0, 0, 0);
        }
    }
    __syncthreads();   // all frag reads done before Ts reuse / epilogue

    const int bb = m0 >> 11;        // batch (tile never crosses batch)
    const int s0 = m0 & 2047;

    if (n0 < 2560) {
        // ---- Q or K head: RoPE in registers, direct bf16 stores ----
        const bool isQ = (n0 < 2048);
        const int h = isQ ? (n0 >> 7) : ((n0 - 2048) >> 7);
        unsigned short* dstbase = isQ
            ? Qh + (((size_t)bb * H_   + h) * S_) * HD_
            : Kh + (((size_t)bb * KVH_ + h) * S_) * HD_;
        float inv[4];
        #pragma unroll
        for (int jm = 0; jm < 4; ++jm)
            inv[jm] = exp2f(-(float)(jm * 16 + lo16) * 0.20761871093344086f);
        #pragma unroll
        for (int i = 0; i < 2; ++i) {
            #pragma unroll
            for (int r = 0; r < 4; ++r) {
                int s = s0 + w * 32 + i * 16 + quad * 4 + r;
                unsigned short* drow = dstbase + (size_t)s * HD_;
                #pragma unroll
                for (int jm = 0; jm < 4; ++jm) {
                    float ang = (float)s * inv[jm];
                    float sn, c;
                    sincosf(ang, &sn, &c);
                    float lo = acc[i][jm][r], hi = acc[i][jm + 4][r];
                    drow[     jm * 16 + lo16] = f2bf(lo * c - hi * sn);
                    drow[64 + jm * 16 + lo16] = f2bf(hi * c + lo * sn);
                }
            }
        }
    } else {
        // ---- V head: transpose via LDS, coalesced b128 stores to Vt[d][s] ----
        const int g = (n0 - 2560) >> 7;
        #pragma unroll
        for (int i = 0; i < 2; ++i)
            #pragma unroll
            for (int jj = 0; jj < 8; ++jj)
                #pragma unroll
                for (int r = 0; r < 4; ++r)
                    Ts[(size_t)(jj * 16 + lo16) * 136 + (w * 32 + i * 16 + quad * 4 + r)]
                        = f2bf(acc[i][jj][r]);
        __syncthreads();
        unsigned short* dstbase = Vt + (((size_t)bb * KVH_ + g) * HD_) * S_ + s0;
        #pragma unroll
        for (int it = 0; it < 8; ++it) {
            int u = it * 256 + tid;
            int d = u >> 4, ch = (u & 15) * 8;
            *(bf16x8*)(dstbase + (size_t)d * S_ + ch) = *(const bf16x8*)&Ts[(size_t)d * 136 + ch];
        }
    }
}

// ---------------------------------------------------------------------------
// bf16 MFMA flash attention (causal, GQA) — verified in R2; epilogue -> bf16.
// ---------------------------------------------------------------------------
__global__ __launch_bounds__(256) void flash_attn_mfma(
    const unsigned short* __restrict__ Qh,
    const unsigned short* __restrict__ Kh,
    const unsigned short* __restrict__ Vt,
    unsigned short* __restrict__ attb)
{
    const int qt   = 31 - blockIdx.x;      // heavy tiles first
    const int bh   = blockIdx.y;
    const int b    = bh >> 4, h = bh & 15;
    const int g    = h >> 2;
    const int tid  = threadIdx.x;
    const int w    = tid >> 6;
    const int lane = tid & 63;
    const int lo16 = lane & 15;
    const int quad = lane >> 4;

    const int q0 = qt * 64;

    const unsigned short* Qb = Qh + (((size_t)b * H_   + h) * S_) * HD_;
    const unsigned short* Kb = Kh + (((size_t)b * KVH_ + g) * S_) * HD_;
    const unsigned short* Vb = Vt + (((size_t)b * KVH_ + g) * HD_) * S_;

    __shared__ __align__(16) unsigned short Ks[64][136];
    __shared__ __align__(16) unsigned short Vs[128][72];
    __shared__ __align__(16) unsigned short Ps[4][16][72];

    bf16x8 qf[4];
    #pragma unroll
    for (int kc = 0; kc < 4; ++kc)
        qf[kc] = *(const bf16x8*)(Qb + (size_t)(q0 + w * 16 + lo16) * HD_
                                     + kc * 32 + quad * 8);

    f32x4 o[8];
    #pragma unroll
    for (int n = 0; n < 8; ++n) o[n] = (f32x4){0.f, 0.f, 0.f, 0.f};
    float m_run[4], l_run[4];
    #pragma unroll
    for (int r = 0; r < 4; ++r) { m_run[r] = -1e30f; l_run[r] = 0.0f; }

    const float scale = 0.08838834764831845f;  // 1/sqrt(128)

    for (int kt = 0; kt <= qt; ++kt) {
        const int k0 = kt * 64;
        __syncthreads();
        #pragma unroll
        for (int it = 0; it < 4; ++it) {
            int u = it * 256 + tid;
            int r = u >> 4, ch = u & 15;
            bf16x8 v = *(const bf16x8*)(Kb + (size_t)(k0 + r) * HD_ + ch * 8);
            *(bf16x8*)&Ks[r][ch * 8] = v;
        }
        #pragma unroll
        for (int it = 0; it < 4; ++it) {
            int u = it * 256 + tid;
            int d = u >> 3, ch = u & 7;
            bf16x8 v = *(const bf16x8*)(Vb + (size_t)d * S_ + k0 + ch * 8);
            *(bf16x8*)&Vs[d][ch * 8] = v;
        }
        __syncthreads();

        f32x4 sc[4];
        #pragma unroll
        for (int cb = 0; cb < 4; ++cb) sc[cb] = (f32x4){0.f, 0.f, 0.f, 0.f};
        #pragma unroll
        for (int kc = 0; kc < 4; ++kc) {
            #pragma unroll
            for (int cb = 0; cb < 4; ++cb) {
                bf16x8 kf = *(const bf16x8*)&Ks[cb * 16 + lo16][kc * 32 + quad * 8];
                sc[cb] = __builtin_amdgcn_mfma_f32_16x16x32_bf16(qf[kc], kf, sc[cb], 0, 0, 0);
            }
        }

        const bool diag = (kt == qt);
        #pragma unroll
        for (int r = 0; r < 4; ++r) {
            int qrow = q0 + w * 16 + quad * 4 + r;
            float sv[4];
            #pragma unroll
            for (int cb = 0; cb < 4; ++cb) {
                float xv = sc[cb][r] * scale;
                if (diag && (k0 + cb * 16 + lo16) > qrow) xv = -1e30f;
                sv[cb] = xv;
            }
            float mt = fmaxf(fmaxf(sv[0], sv[1]), fmaxf(sv[2], sv[3]));
            #pragma unroll
            for (int off = 1; off < 16; off <<= 1)
                mt = fmaxf(mt, __shfl_xor(mt, off));
            float m_new = fmaxf(m_run[r], mt);
            float alpha = __expf(m_run[r] - m_new);
            float psum = 0.0f;
            #pragma unroll
            for (int cb = 0; cb < 4; ++cb) {
                float p = __expf(sv[cb] - m_new);
                psum += p;
                Ps[w][quad * 4 + r][cb * 16 + lo16] = f2bf(p);
            }
            #pragma unroll
            for (int off = 1; off < 16; off <<= 1)
                psum += __shfl_xor(psum, off);
            m_run[r] = m_new;
            l_run[r] = l_run[r] * alpha + psum;
            #pragma unroll
            for (int n = 0; n < 8; ++n) o[n][r] *= alpha;
        }

        #pragma unroll
        for (int kc = 0; kc < 2; ++kc) {
            bf16x8 pf = *(const bf16x8*)&Ps[w][lo16][kc * 32 + quad * 8];
            #pragma unroll
            for (int n = 0; n < 8; ++n) {
                bf16x8 vf = *(const bf16x8*)&Vs[n * 16 + lo16][kc * 32 + quad * 8];
                o[n] = __builtin_amdgcn_mfma_f32_16x16x32_bf16(pf, vf, o[n], 0, 0, 0);
            }
        }
    }

    #pragma unroll
    for (int r = 0; r < 4; ++r) {
        int srow   = q0 + w * 16 + quad * 4 + r;
        float invl = 1.0f / l_run[r];
        unsigned short* dst = attb + ((size_t)b * S_ + srow) * D_ + h * HD_;
        #pragma unroll
        for (int n = 0; n < 8; ++n)
            dst[n * 16 + lo16] = f2bf(o[n][r] * invl);
    }
}

// ---------------------------------------------------------------------------
// Output projection, bf16 MFMA: out[4096][2048] = attb . Wot[n][k]^T (fp32 out)
// ---------------------------------------------------------------------------
__global__ __launch_bounds__(256) void out_mfma(
    const unsigned short* __restrict__ Ah,    // attb [4096][2048]
    const unsigned short* __restrict__ Wot,   // [2048][2048]
    float* __restrict__ C)
{
    __shared__ __align__(16) unsigned short As[128 * 32];
    __shared__ __align__(16) unsigned short Bs[128 * 32];

    const int bm = blockIdx.x, bn = blockIdx.y;
    const int m0 = bm * 128, n0 = bn * 128;
    const int tid  = threadIdx.x;
    const int w    = tid >> 6;
    const int lane = tid & 63;
    const int lo16 = lane & 15, quad = lane >> 4;

    const unsigned short* Ag = Ah  + (size_t)m0 * 2048;
    const unsigned short* Bt = Wot + (size_t)n0 * 2048;

    f32x4 acc[2][8];
    #pragma unroll
    for (int i = 0; i < 2; ++i)
        #pragma unroll
        for (int j = 0; j < 8; ++j) acc[i][j] = (f32x4){0.f, 0.f, 0.f, 0.f};

    const int srow = w * 32 + (lane >> 2);
    const int scol = (lane & 3) * 8;

    for (int kt = 0; kt < 2048; kt += 32) {
        __syncthreads();
        gl_lds16(Ag + (size_t)(srow     ) * 2048 + kt + scol, As + (w * 32     ) * 32);
        gl_lds16(Ag + (size_t)(srow + 16) * 2048 + kt + scol, As + (w * 32 + 16) * 32);
        gl_lds16(Bt + (size_t)(srow     ) * 2048 + kt + scol, Bs + (w * 32     ) * 32);
        gl_lds16(Bt + (size_t)(srow + 16) * 2048 + kt + scol, Bs + (w * 32 + 16) * 32);
        __syncthreads();

        bf16x8 a0 = *(const bf16x8*)&As[(w * 32      + lo16) * 32 + quad * 8];
        bf16x8 a1 = *(const bf16x8*)&As[(w * 32 + 16 + lo16) * 32 + quad * 8];
        #pragma unroll
        for (int jj = 0; jj < 8; ++jj) {
            bf16x8 b = *(const bf16x8*)&Bs[(jj * 16 + lo16) * 32 + quad * 8];
            acc[0][jj] = __builtin_amdgcn_mfma_f32_16x16x32_bf16(a0, b, acc[0][jj], 0, 0, 0);
            acc[1][jj] = __builtin_amdgcn_mfma_f32_16x16x32_bf16(a1, b, acc[1][jj], 0, 0, 0);
        }
    }

    #pragma unroll
    for (int i = 0; i < 2; ++i)
        #pragma unroll
        for (int r = 0; r < 4; ++r) {
            size_t m = (size_t)(m0 + w * 32 + i * 16 + quad * 4 + r);
            #pragma unroll
            for (int jj = 0; jj < 8; ++jj)
                C[m * 2048 + n0 + jj * 16 + lo16] = acc[i][jj][r];
        }
}

// ---------------------------------------------------------------------------
extern "C" void kernel_launch(void* const* d_in, const int* in_sizes, int n_in,
                              void* d_out, int out_size, void* d_ws, size_t ws_size,
                              hipStream_t stream)
{
    const float* x  = (const float*)d_in[0];
    const float* Wq = (const float*)d_in[1];
    const float* Wk = (const float*)d_in[2];
    const float* Wv = (const float*)d_in[3];
    const float* Wo = (const float*)d_in[4];
    float* out = (float*)d_out;

    // ws layout (all bf16 shorts): xh 8.4M | Wqt 4.2M | Wkt 1M | Wvt 1M |
    // Wot 4.2M | Qh 8.4M | Kh 2.1M | Vt 2.1M | attb 8.4M  (~80 MB)
    unsigned short* xh  = (unsigned short*)d_ws;
    unsigned short* Wqt = xh  + (size_t)4096 * 2048;
    unsigned short* Wkt = Wqt + (size_t)2048 * 2048;
    unsigned short* Wvt = Wkt + (size_t)512 * 2048;
    unsigned short* Wot = Wvt + (size_t)512 * 2048;
    unsigned short* Qh  = Wot + (size_t)2048 * 2048;
    unsigned short* Kh  = Qh  + (size_t)B_ * H_   * S_ * HD_;
    unsigned short* Vt  = Kh  + (size_t)B_ * KVH_ * S_ * HD_;
    unsigned short* attb= Vt  + (size_t)B_ * KVH_ * S_ * HD_;

    cast_bf16<<<(4096 * 2048 / 4 + 255) / 256, 256, 0, stream>>>(x, xh, 4096 * 2048 / 4);
    cast_transpose<<<dim3(64, 64), 256, 0, stream>>>(Wq, Wqt, 2048, 2048);
    cast_transpose<<<dim3(64, 16), 256, 0, stream>>>(Wk, Wkt, 2048, 512);
    cast_transpose<<<dim3(64, 16), 256, 0, stream>>>(Wv, Wvt, 2048, 512);
    cast_transpose<<<dim3(64, 64), 256, 0, stream>>>(Wo, Wot, 2048, 2048);

    qkv_mfma<<<dim3(32, 24), 256, 0, stream>>>(xh, Wqt, Wkt, Wvt, Qh, Kh, Vt);

    flash_attn_mfma<<<dim3(32, 32), 256, 0, stream>>>(Qh, Kh, Vt, attb);

    out_mfma<<<dim3(32, 16), 256, 0, stream>>>(attb, Wot, out);
}

// Round 4
// 362.680 us; speedup vs baseline: 61.5526x; 1.5199x over previous
//
#include <hip/hip_runtime.h>
#include <math.h>

#define B_   2
#define S_   2048
#define D_   2048
#define H_   16
#define KVH_ 4
#define HD_  128
#define REP_ 4

typedef __attribute__((ext_vector_type(8))) short bf16x8;
typedef __attribute__((ext_vector_type(4))) short bf16x4;
typedef __attribute__((ext_vector_type(4))) float f32x4;

// 1/sqrt(128) * log2(e): folded into Q so flash scores are base-2 pre-scaled
#define QSCALE_LOG2E 0.12752669770972建f
#undef QSCALE_LOG2E
#define QSCALE_LOG2E 0.1275266977097153f

__device__ __forceinline__ unsigned short f2bf(float x) {
    union { float f; unsigned u; } v; v.f = x;
    unsigned r = v.u + 0x7FFF + ((v.u >> 16) & 1);   // RNE
    return (unsigned short)(r >> 16);
}

// async global->LDS, 16B per lane; LDS dest is wave-uniform base + lane*16
__device__ __forceinline__ void gl_lds16(const unsigned short* g, unsigned short* l) {
    __builtin_amdgcn_global_load_lds(
        (const __attribute__((address_space(1))) unsigned int*)g,
        (__attribute__((address_space(3))) unsigned int*)l,
        16, 0, 0);
}

// ---------------------------------------------------------------------------
// cast fp32 -> bf16 (elementwise)
// ---------------------------------------------------------------------------
__global__ void cast_bf16(const float* __restrict__ src,
                          unsigned short* __restrict__ dst, int n4)
{
    int i = blockIdx.x * 256 + threadIdx.x;
    if (i >= n4) return;
    float4 v = *(const float4*)&src[(size_t)i * 4];
    bf16x4 o;
    o[0] = (short)f2bf(v.x); o[1] = (short)f2bf(v.y);
    o[2] = (short)f2bf(v.z); o[3] = (short)f2bf(v.w);
    *(bf16x4*)&dst[(size_t)i * 4] = o;
}

// ---------------------------------------------------------------------------
// fused cast+transpose of all 4 weights: src [2048][C] fp32 -> dst [C][2048].
// blockIdx.y selects the weight: [0,64) Wq | [64,80) Wk | [80,96) Wv | [96,160) Wo
// ---------------------------------------------------------------------------
__global__ __launch_bounds__(256) void cast_transpose_all(
    const float* __restrict__ Wq, const float* __restrict__ Wk,
    const float* __restrict__ Wv, const float* __restrict__ Wo,
    unsigned short* __restrict__ Wqt, unsigned short* __restrict__ Wkt,
    unsigned short* __restrict__ Wvt, unsigned short* __restrict__ Wot)
{
    __shared__ float T[32][33];
    const int y = blockIdx.y;
    const float* src; unsigned short* dst; int C, bj;
    if (y < 64)      { src = Wq; dst = Wqt; C = 2048; bj = y; }
    else if (y < 80) { src = Wk; dst = Wkt; C = 512;  bj = y - 64; }
    else if (y < 96) { src = Wv; dst = Wvt; C = 512;  bj = y - 80; }
    else             { src = Wo; dst = Wot; C = 2048; bj = y - 96; }

    const int bi = blockIdx.x;   // along R=2048
    const int t  = threadIdx.x;
    const int r  = t >> 3, cq = (t & 7) * 4;

    float4 v = *(const float4*)&src[(size_t)(bi * 32 + r) * C + bj * 32 + cq];
    T[r][cq + 0] = v.x; T[r][cq + 1] = v.y;
    T[r][cq + 2] = v.z; T[r][cq + 3] = v.w;
    __syncthreads();

    bf16x4 o;
    o[0] = (short)f2bf(T[cq + 0][r]);
    o[1] = (short)f2bf(T[cq + 1][r]);
    o[2] = (short)f2bf(T[cq + 2][r]);
    o[3] = (short)f2bf(T[cq + 3][r]);
    *(bf16x4*)&dst[(size_t)(bj * 32 + r) * 2048 + bi * 32 + cq] = o;
}

// ---------------------------------------------------------------------------
// Fused QKV projection, bf16 MFMA (m97 structure), RoPE fused.
// Q additionally scaled by 1/sqrt(HD)*log2(e)  (softmax runs in base-2).
//   Qh (B,H,S,HD) | Kh (B,KVH,S,HD) | Vt (B,KVH,HD,S)  all bf16.
// ---------------------------------------------------------------------------
__global__ __launch_bounds__(256) void qkv_mfma(
    const unsigned short* __restrict__ Ah,    // xh [4096][2048]
    const unsigned short* __restrict__ Wqt,   // [2048][2048]
    const unsigned short* __restrict__ Wkt,   // [512][2048]
    const unsigned short* __restrict__ Wvt,   // [512][2048]
    unsigned short* __restrict__ Qh, unsigned short* __restrict__ Kh,
    unsigned short* __restrict__ Vt)
{
    __shared__ __align__(16) char smem[34816];
    unsigned short* As = (unsigned short*)smem;            // [128][32]
    unsigned short* Bs = (unsigned short*)(smem + 8192);   // [128][32]
    unsigned short* Ts = (unsigned short*)smem;            // [128][136] (V only)

    const int bm = blockIdx.x, bn = blockIdx.y;
    const int m0 = bm * 128, n0 = bn * 128;
    const int tid  = threadIdx.x;
    const int w    = tid >> 6;
    const int lane = tid & 63;
    const int lo16 = lane & 15, quad = lane >> 4;

    const unsigned short* Bt;
    if (n0 < 2048)      Bt = Wqt + (size_t)n0 * 2048;
    else if (n0 < 2560) Bt = Wkt + (size_t)(n0 - 2048) * 2048;
    else                Bt = Wvt + (size_t)(n0 - 2560) * 2048;

    const unsigned short* Ag = Ah + (size_t)m0 * 2048;

    f32x4 acc[2][8];
    #pragma unroll
    for (int i = 0; i < 2; ++i)
        #pragma unroll
        for (int j = 0; j < 8; ++j) acc[i][j] = (f32x4){0.f, 0.f, 0.f, 0.f};

    const int srow = w * 32 + (lane >> 2);
    const int scol = (lane & 3) * 8;

    for (int kt = 0; kt < 2048; kt += 32) {
        __syncthreads();
        gl_lds16(Ag + (size_t)(srow     ) * 2048 + kt + scol, As + (w * 32     ) * 32);
        gl_lds16(Ag + (size_t)(srow + 16) * 2048 + kt + scol, As + (w * 32 + 16) * 32);
        gl_lds16(Bt + (size_t)(srow     ) * 2048 + kt + scol, Bs + (w * 32     ) * 32);
        gl_lds16(Bt + (size_t)(srow + 16) * 2048 + kt + scol, Bs + (w * 32 + 16) * 32);
        __syncthreads();

        bf16x8 a0 = *(const bf16x8*)&As[(w * 32      + lo16) * 32 + quad * 8];
        bf16x8 a1 = *(const bf16x8*)&As[(w * 32 + 16 + lo16) * 32 + quad * 8];
        #pragma unroll
        for (int jj = 0; jj < 8; ++jj) {
            bf16x8 b = *(const bf16x8*)&Bs[(jj * 16 + lo16) * 32 + quad * 8];
            acc[0][jj] = __builtin_amdgcn_mfma_f32_16x16x32_bf16(a0, b, acc[0][jj], 0, 0, 0);
            acc[1][jj] = __builtin_amdgcn_mfma_f32_16x16x32_bf16(a1, b, acc[1][jj], 0, 0, 0);
        }
    }
    __syncthreads();

    const int bb = m0 >> 11;
    const int s0 = m0 & 2047;

    if (n0 < 2560) {
        const bool isQ = (n0 < 2048);
        const int h = isQ ? (n0 >> 7) : ((n0 - 2048) >> 7);
        const float post = isQ ? QSCALE_LOG2E : 1.0f;
        unsigned short* dstbase = isQ
            ? Qh + (((size_t)bb * H_   + h) * S_) * HD_
            : Kh + (((size_t)bb * KVH_ + h) * S_) * HD_;
        float inv[4];
        #pragma unroll
        for (int jm = 0; jm < 4; ++jm)
            inv[jm] = exp2f(-(float)(jm * 16 + lo16) * 0.20761871093344086f);
        #pragma unroll
        for (int i = 0; i < 2; ++i) {
            #pragma unroll
            for (int r = 0; r < 4; ++r) {
                int s = s0 + w * 32 + i * 16 + quad * 4 + r;
                unsigned short* drow = dstbase + (size_t)s * HD_;
                #pragma unroll
                for (int jm = 0; jm < 4; ++jm) {
                    float ang = (float)s * inv[jm];
                    float sn, c;
                    sincosf(ang, &sn, &c);
                    float lo = acc[i][jm][r], hi = acc[i][jm + 4][r];
                    drow[     jm * 16 + lo16] = f2bf((lo * c - hi * sn) * post);
                    drow[64 + jm * 16 + lo16] = f2bf((hi * c + lo * sn) * post);
                }
            }
        }
    } else {
        const int g = (n0 - 2560) >> 7;
        #pragma unroll
        for (int i = 0; i < 2; ++i)
            #pragma unroll
            for (int jj = 0; jj < 8; ++jj)
                #pragma unroll
                for (int r = 0; r < 4; ++r)
                    Ts[(size_t)(jj * 16 + lo16) * 136 + (w * 32 + i * 16 + quad * 4 + r)]
                        = f2bf(acc[i][jj][r]);
        __syncthreads();
        unsigned short* dstbase = Vt + (((size_t)bb * KVH_ + g) * HD_) * S_ + s0;
        #pragma unroll
        for (int it = 0; it < 8; ++it) {
            int u = it * 256 + tid;
            int d = u >> 4, ch = (u & 15) * 8;
            *(bf16x8*)(dstbase + (size_t)d * S_ + ch) = *(const bf16x8*)&Ts[(size_t)d * 136 + ch];
        }
    }
}

// ---------------------------------------------------------------------------
// bf16 MFMA flash attention (causal, GQA), register-prefetched K/V staging,
// causal-paired tiles: block z does qt=31-z then qt=z (uniform 33 iters).
// Scores arrive pre-scaled by log2e/sqrt(HD) (folded into Q) -> exp2f softmax.
// ---------------------------------------------------------------------------
__global__ __launch_bounds__(256) void flash_attn_mfma(
    const unsigned short* __restrict__ Qh,
    const unsigned short* __restrict__ Kh,
    const unsigned short* __restrict__ Vt,
    unsigned short* __restrict__ attb)
{
    const int z    = blockIdx.x;           // 0..15
    const int bh   = blockIdx.y;
    const int b    = bh >> 4, h = bh & 15;
    const int g    = h >> 2;
    const int tid  = threadIdx.x;
    const int w    = tid >> 6;
    const int lane = tid & 63;
    const int lo16 = lane & 15;
    const int quad = lane >> 4;

    const unsigned short* Qb = Qh + (((size_t)b * H_   + h) * S_) * HD_;
    const unsigned short* Kb = Kh + (((size_t)b * KVH_ + g) * S_) * HD_;
    const unsigned short* Vb = Vt + (((size_t)b * KVH_ + g) * HD_) * S_;

    __shared__ __align__(16) unsigned short Ks[64][136];
    __shared__ __align__(16) unsigned short Vs[128][72];
    __shared__ __align__(16) unsigned short Ps[4][16][72];

    // staging coords (constant per thread)
    const int kr  = tid >> 4;        // K row base within 16-row group
    const int kch = (tid & 15) * 8;  // K col chunk
    const int vd  = tid >> 3;        // V row base within 32-row group
    const int vch = (tid & 7) * 8;   // V col chunk

    #pragma unroll
    for (int pass = 0; pass < 2; ++pass) {
        const int qt = (pass == 0) ? (31 - z) : z;
        const int q0 = qt * 64;

        bf16x8 qf[4];
        #pragma unroll
        for (int kc = 0; kc < 4; ++kc)
            qf[kc] = *(const bf16x8*)(Qb + (size_t)(q0 + w * 16 + lo16) * HD_
                                         + kc * 32 + quad * 8);

        f32x4 o[8];
        #pragma unroll
        for (int n = 0; n < 8; ++n) o[n] = (f32x4){0.f, 0.f, 0.f, 0.f};
        float m_run[4], l_run[4];
        #pragma unroll
        for (int r = 0; r < 4; ++r) { m_run[r] = -1e30f; l_run[r] = 0.0f; }

        // preload kv-tile 0 into registers
        bf16x8 kreg[4], vreg[4];
        #pragma unroll
        for (int it = 0; it < 4; ++it) {
            kreg[it] = *(const bf16x8*)(Kb + (size_t)(it * 16 + kr) * HD_ + kch);
            vreg[it] = *(const bf16x8*)(Vb + (size_t)(it * 32 + vd) * S_ + vch);
        }

        for (int kt = 0; kt <= qt; ++kt) {
            const int k0 = kt * 64;
            __syncthreads();                 // prior tile's LDS reads complete
            #pragma unroll
            for (int it = 0; it < 4; ++it) {
                *(bf16x8*)&Ks[it * 16 + kr][kch] = kreg[it];
                *(bf16x8*)&Vs[it * 32 + vd][vch] = vreg[it];
            }
            if (kt < qt) {                   // prefetch tile kt+1 (uniform branch)
                const int k0n = k0 + 64;
                #pragma unroll
                for (int it = 0; it < 4; ++it) {
                    kreg[it] = *(const bf16x8*)(Kb + (size_t)(k0n + it * 16 + kr) * HD_ + kch);
                    vreg[it] = *(const bf16x8*)(Vb + (size_t)(it * 32 + vd) * S_ + k0n + vch);
                }
            }
            __syncthreads();

            // S strip (16x64) = Q_strip . K^T   (pre-scaled, base-2 domain)
            f32x4 sc[4];
            #pragma unroll
            for (int cb = 0; cb < 4; ++cb) sc[cb] = (f32x4){0.f, 0.f, 0.f, 0.f};
            #pragma unroll
            for (int kc = 0; kc < 4; ++kc) {
                #pragma unroll
                for (int cb = 0; cb < 4; ++cb) {
                    bf16x8 kf = *(const bf16x8*)&Ks[cb * 16 + lo16][kc * 32 + quad * 8];
                    sc[cb] = __builtin_amdgcn_mfma_f32_16x16x32_bf16(qf[kc], kf, sc[cb], 0, 0, 0);
                }
            }

            const bool diag = (kt == qt);
            #pragma unroll
            for (int r = 0; r < 4; ++r) {
                int qrow = q0 + w * 16 + quad * 4 + r;
                float sv[4];
                #pragma unroll
                for (int cb = 0; cb < 4; ++cb) {
                    float xv = sc[cb][r];
                    if (diag && (k0 + cb * 16 + lo16) > qrow) xv = -1e30f;
                    sv[cb] = xv;
                }
                float mt = fmaxf(fmaxf(sv[0], sv[1]), fmaxf(sv[2], sv[3]));
                #pragma unroll
                for (int off = 1; off < 16; off <<= 1)
                    mt = fmaxf(mt, __shfl_xor(mt, off));
                float m_new = fmaxf(m_run[r], mt);
                float alpha = exp2f(m_run[r] - m_new);
                float psum = 0.0f;
                #pragma unroll
                for (int cb = 0; cb < 4; ++cb) {
                    float p = exp2f(sv[cb] - m_new);
                    psum += p;
                    Ps[w][quad * 4 + r][cb * 16 + lo16] = f2bf(p);
                }
                #pragma unroll
                for (int off = 1; off < 16; off <<= 1)
                    psum += __shfl_xor(psum, off);
                m_run[r] = m_new;
                l_run[r] = l_run[r] * alpha + psum;
                #pragma unroll
                for (int n = 0; n < 8; ++n) o[n][r] *= alpha;
            }
            // Ps[w] is wave-private; lgkm ordering handles the RAW

            // O strip += P (16x64) . V (64x128)
            #pragma unroll
            for (int kc = 0; kc < 2; ++kc) {
                bf16x8 pf = *(const bf16x8*)&Ps[w][lo16][kc * 32 + quad * 8];
                #pragma unroll
                for (int n = 0; n < 8; ++n) {
                    bf16x8 vf = *(const bf16x8*)&Vs[n * 16 + lo16][kc * 32 + quad * 8];
                    o[n] = __builtin_amdgcn_mfma_f32_16x16x32_bf16(pf, vf, o[n], 0, 0, 0);
                }
            }
        }

        // epilogue: attb (B, S, H*HD) bf16
        #pragma unroll
        for (int r = 0; r < 4; ++r) {
            int srow   = q0 + w * 16 + quad * 4 + r;
            float invl = 1.0f / l_run[r];
            unsigned short* dst = attb + ((size_t)b * S_ + srow) * D_ + h * HD_;
            #pragma unroll
            for (int n = 0; n < 8; ++n)
                dst[n * 16 + lo16] = f2bf(o[n][r] * invl);
        }
    }
}

// ---------------------------------------------------------------------------
// Output projection, bf16 MFMA: out[4096][2048] = attb . Wot^T (fp32 out)
// ---------------------------------------------------------------------------
__global__ __launch_bounds__(256) void out_mfma(
    const unsigned short* __restrict__ Ah,
    const unsigned short* __restrict__ Wot,
    float* __restrict__ C)
{
    __shared__ __align__(16) unsigned short As[128 * 32];
    __shared__ __align__(16) unsigned short Bs[128 * 32];

    const int bm = blockIdx.x, bn = blockIdx.y;
    const int m0 = bm * 128, n0 = bn * 128;
    const int tid  = threadIdx.x;
    const int w    = tid >> 6;
    const int lane = tid & 63;
    const int lo16 = lane & 15, quad = lane >> 4;

    const unsigned short* Ag = Ah  + (size_t)m0 * 2048;
    const unsigned short* Bt = Wot + (size_t)n0 * 2048;

    f32x4 acc[2][8];
    #pragma unroll
    for (int i = 0; i < 2; ++i)
        #pragma unroll
        for (int j = 0; j < 8; ++j) acc[i][j] = (f32x4){0.f, 0.f, 0.f, 0.f};

    const int srow = w * 32 + (lane >> 2);
    const int scol = (lane & 3) * 8;

    for (int kt = 0; kt < 2048; kt += 32) {
        __syncthreads();
        gl_lds16(Ag + (size_t)(srow     ) * 2048 + kt + scol, As + (w * 32     ) * 32);
        gl_lds16(Ag + (size_t)(srow + 16) * 2048 + kt + scol, As + (w * 32 + 16) * 32);
        gl_lds16(Bt + (size_t)(srow     ) * 2048 + kt + scol, Bs + (w * 32     ) * 32);
        gl_lds16(Bt + (size_t)(srow + 16) * 2048 + kt + scol, Bs + (w * 32 + 16) * 32);
        __syncthreads();

        bf16x8 a0 = *(const bf16x8*)&As[(w * 32      + lo16) * 32 + quad * 8];
        bf16x8 a1 = *(const bf16x8*)&As[(w * 32 + 16 + lo16) * 32 + quad * 8];
        #pragma unroll
        for (int jj = 0; jj < 8; ++jj) {
            bf16x8 b = *(const bf16x8*)&Bs[(jj * 16 + lo16) * 32 + quad * 8];
            acc[0][jj] = __builtin_amdgcn_mfma_f32_16x16x32_bf16(a0, b, acc[0][jj], 0, 0, 0);
            acc[1][jj] = __builtin_amdgcn_mfma_f32_16x16x32_bf16(a1, b, acc[1][jj], 0, 0, 0);
        }
    }

    #pragma unroll
    for (int i = 0; i < 2; ++i)
        #pragma unroll
        for (int r = 0; r < 4; ++r) {
            size_t m = (size_t)(m0 + w * 32 + i * 16 + quad * 4 + r);
            #pragma unroll
            for (int jj = 0; jj < 8; ++jj)
                C[m * 2048 + n0 + jj * 16 + lo16] = acc[i][jj][r];
        }
}

// ---------------------------------------------------------------------------
extern "C" void kernel_launch(void* const* d_in, const int* in_sizes, int n_in,
                              void* d_out, int out_size, void* d_ws, size_t ws_size,
                              hipStream_t stream)
{
    const float* x  = (const float*)d_in[0];
    const float* Wq = (const float*)d_in[1];
    const float* Wk = (const float*)d_in[2];
    const float* Wv = (const float*)d_in[3];
    const float* Wo = (const float*)d_in[4];
    float* out = (float*)d_out;

    unsigned short* xh  = (unsigned short*)d_ws;
    unsigned short* Wqt = xh  + (size_t)4096 * 2048;
    unsigned short* Wkt = Wqt + (size_t)2048 * 2048;
    unsigned short* Wvt = Wkt + (size_t)512 * 2048;
    unsigned short* Wot = Wvt + (size_t)512 * 2048;
    unsigned short* Qh  = Wot + (size_t)2048 * 2048;
    unsigned short* Kh  = Qh  + (size_t)B_ * H_   * S_ * HD_;
    unsigned short* Vt  = Kh  + (size_t)B_ * KVH_ * S_ * HD_;
    unsigned short* attb= Vt  + (size_t)B_ * KVH_ * S_ * HD_;

    cast_bf16<<<(4096 * 2048 / 4 + 255) / 256, 256, 0, stream>>>(x, xh, 4096 * 2048 / 4);
    cast_transpose_all<<<dim3(64, 160), 256, 0, stream>>>(Wq, Wk, Wv, Wo, Wqt, Wkt, Wvt, Wot);

    qkv_mfma<<<dim3(32, 24), 256, 0, stream>>>(xh, Wqt, Wkt, Wvt, Qh, Kh, Vt);

    flash_attn_mfma<<<dim3(16, 32), 256, 0, stream>>>(Qh, Kh, Vt, attb);

    out_mfma<<<dim3(32, 16), 256, 0, stream>>>(attb, Wot, out);
}